// Round 1
// baseline (70.643 us; speedup 1.0000x reference)
//
#include <hip/hip_runtime.h>
#include <math.h>

#define NB 8192
#define NK 64
#define NGLOBAL 16384
#define INV_T 0.5f   // 1/TEMPERATURE

// ---------------------------------------------------------------------------
// Kernel 1: scatter g2l[batch_indices[i]] = i  (table pre-filled with -1 via
// hipMemsetAsync 0xFF).
// ---------------------------------------------------------------------------
__global__ void g2l_scatter_kernel(const int* __restrict__ bidx,
                                   int* __restrict__ g2l, int b) {
    int i = blockIdx.x * blockDim.x + threadIdx.x;
    if (i < b) {
        int g = bidx[i];
        if ((unsigned)g < (unsigned)NGLOBAL) g2l[g] = i;  // OOB dropped
    }
}

// ---------------------------------------------------------------------------
// Kernel 2: one block per row.
//  - single-pass row read into registers (8 x float4 per thread, coalesced)
//  - block max + sumexp  -> lse of logits/T
//  - threads 0..63 (wave 0) handle the K teacher entries: g2l lookup,
//    last-wins dedup, diagonal override, KL pointwise terms
//  - per-row partial written to ws
// ---------------------------------------------------------------------------
__global__ __launch_bounds__(256) void row_loss_kernel(
    const float* __restrict__ S,        // [NB, NB] student logits
    const float* __restrict__ tscore,   // [NB, NK]
    const int* __restrict__ tindex,     // [NB, NK]
    const int* __restrict__ g2l,        // [NGLOBAL]
    float* __restrict__ row_out)        // [NB]
{
    const int row = blockIdx.x;
    const int t = threadIdx.x;
    const float4* rp = reinterpret_cast<const float4*>(S + (size_t)row * NB);

    // ---- load row into registers (coalesced) ----
    float4 v[8];
#pragma unroll
    for (int i = 0; i < 8; ++i) v[i] = rp[i * 256 + t];

    // ---- block max ----
    float m = -INFINITY;
#pragma unroll
    for (int i = 0; i < 8; ++i)
        m = fmaxf(m, fmaxf(fmaxf(v[i].x, v[i].y), fmaxf(v[i].z, v[i].w)));
#pragma unroll
    for (int off = 32; off >= 1; off >>= 1) m = fmaxf(m, __shfl_xor(m, off));

    __shared__ float sred[4];
    if ((t & 63) == 0) sred[t >> 6] = m;
    __syncthreads();
    m = fmaxf(fmaxf(sred[0], sred[1]), fmaxf(sred[2], sred[3]));
    const float M = m * INV_T;  // max of x = s/T (scale > 0, monotone)

    // ---- block sum of exp(x - M) ----
    float s = 0.f;
#pragma unroll
    for (int i = 0; i < 8; ++i) {
        s += expf(v[i].x * INV_T - M);
        s += expf(v[i].y * INV_T - M);
        s += expf(v[i].z * INV_T - M);
        s += expf(v[i].w * INV_T - M);
    }
#pragma unroll
    for (int off = 32; off >= 1; off >>= 1) s += __shfl_xor(s, off);
    __syncthreads();                 // all reads of sred (max) done
    if ((t & 63) == 0) sred[t >> 6] = s;
    __syncthreads();
    const float lse = logf(sred[0] + sred[1] + sred[2] + sred[3]) + M;

    // ---- teacher-entry phase ----
    __shared__ int scol[NK];
    __shared__ float sscore[NK];
    if (t < NK) {
        int gi = tindex[(size_t)row * NK + t];
        gi = min(max(gi, 0), NGLOBAL - 1);       // clip like reference
        int col = g2l[gi];
        if (col == row) col = -1;                // diag later forced to 1.0
        scol[t] = col;
        sscore[t] = tscore[(size_t)row * NK + t];
    }
    __syncthreads();
    if (t >= NK) return;             // wave 0 (all 64 lanes) continues

    int col = scol[t];
    float sc = sscore[t];
    bool live = (col >= 0);
    if (live) {                      // last write wins (scatter-set semantics)
        for (int k = t + 1; k < NK; ++k)
            if (scol[k] == col) { live = false; break; }
    }

    float part = live ? sc : 0.f;    // row sum of scattered values
#pragma unroll
    for (int off = 32; off >= 1; off >>= 1) part += __shfl_xor(part, off);
    const float row_sum = 1.0f + part;   // + diagonal 1.0 (>= 1, clip moot)

    float term = 0.f;
    if (live && sc > 0.f) {
        float tv = sc / row_sum;
        float logp = S[(size_t)row * NB + col] * INV_T - lse;
        term = tv * (logf(tv) - logp);
    }
    if (t == 0) {                    // diagonal target = 1/row_sum
        float td = 1.0f / row_sum;
        float logp = S[(size_t)row * NB + row] * INV_T - lse;
        term += td * (logf(td) - logp);
    }
#pragma unroll
    for (int off = 32; off >= 1; off >>= 1) term += __shfl_xor(term, off);
    if (t == 0) row_out[row] = term;
}

// ---------------------------------------------------------------------------
// Kernel 3: reduce 8192 row partials -> scalar loss (double accumulation).
// ---------------------------------------------------------------------------
__global__ __launch_bounds__(256) void final_reduce_kernel(
    const float* __restrict__ row_out, float* __restrict__ out) {
    double acc = 0.0;
    for (int i = threadIdx.x; i < NB; i += 256) acc += (double)row_out[i];
#pragma unroll
    for (int off = 32; off >= 1; off >>= 1) acc += __shfl_xor(acc, off);
    __shared__ double sd[4];
    if ((threadIdx.x & 63) == 0) sd[threadIdx.x >> 6] = acc;
    __syncthreads();
    if (threadIdx.x == 0) {
        double total = sd[0] + sd[1] + sd[2] + sd[3];
        // loss = sum / B * T^2
        out[0] = (float)(total / (double)NB * 4.0);
    }
}

extern "C" void kernel_launch(void* const* d_in, const int* in_sizes, int n_in,
                              void* d_out, int out_size, void* d_ws, size_t ws_size,
                              hipStream_t stream) {
    const float* S      = (const float*)d_in[0];   // student_logits [B,B] f32
    const float* tscore = (const float*)d_in[1];   // teacher_scores [B,K] f32
    const int*   bidx   = (const int*)d_in[2];     // batch_indices [B] i32
    const int*   tindex = (const int*)d_in[3];     // teacher_indices [B,K] i32
    float* out = (float*)d_out;
    const int b = in_sizes[2];                     // = NB

    // workspace layout: [0, 64KB) g2l table, then [64KB, 64KB+32KB) row partials
    int*   g2l     = (int*)d_ws;
    float* row_out = (float*)((char*)d_ws + NGLOBAL * sizeof(int));

    hipMemsetAsync(g2l, 0xFF, NGLOBAL * sizeof(int), stream);  // fill -1
    g2l_scatter_kernel<<<(b + 255) / 256, 256, 0, stream>>>(bidx, g2l, b);
    row_loss_kernel<<<NB, 256, 0, stream>>>(S, tscore, tindex, g2l, row_out);
    final_reduce_kernel<<<1, 256, 0, stream>>>(row_out, out);
}